// Round 9
// baseline (134.186 us; speedup 1.0000x reference)
//
#include <hip/hip_runtime.h>

#define Bq 2
#define Nn 6
#define Dd 48
#define Hh 28
#define Ww 60
#define Cc 64
#define Xd 200
#define Yd 200
#define NP (Nn*Dd*Hh*Ww)      // 483840 points per batch
#define TOTP (Bq*NP)          // 967680 total points
#define NVOX (Xd*Yd)          // 40000 voxels per batch (Z=1)
#define NSEG (Bq*NVOX)        // 80000 segments
#define NB1  79               // ceil(NSEG/1024)
#define CAP  512              // staged point-ids per wave (avg need ~66)
#define RND  32               // points DMA-staged per round per wave

// Zero the histogram ourselves: rocclr fillBufferAligned is pathologically slow
__global__ __launch_bounds__(1024) void zero_cnt(int* __restrict__ cnt)
{
    int i = blockIdx.x * 1024 + threadIdx.x;
    if (i < NSEG) cnt[i] = 0;
}

// ---------------------------------------------------------------------------
// Phase A: voxelize each point, store segment id (-1 invalid), histogram count
// ---------------------------------------------------------------------------
__global__ __launch_bounds__(256) void phase_a(
    const float* __restrict__ geom, int* __restrict__ rank, int* __restrict__ cnt)
{
    int p = blockIdx.x * 256 + threadIdx.x;
    if (p >= TOTP) return;
    float gx = geom[(long)p*3 + 0];
    float gy = geom[(long)p*3 + 1];
    float gz = geom[(long)p*3 + 2];
    // must match numpy astype(int32): truncate toward zero, f32 arithmetic
    int vx = (int)((gx + 50.0f) / 0.5f);
    int vy = (int)((gy + 50.0f) / 0.5f);
    int vz = (int)((gz + 10.0f) / 20.0f);
    int seg = -1;
    if (vx >= 0 && vx < Xd && vy >= 0 && vy < Yd && vz == 0) {
        int b = (p >= NP) ? 1 : 0;
        seg = b * NVOX + vx * Yd + vy;
        atomicAdd(&cnt[seg], 1);
    }
    rank[p] = seg;
}

// Scan P1: per-1024-block exclusive scan of cnt -> start, block totals -> bsum
__global__ __launch_bounds__(1024) void scan_p1(
    const int* __restrict__ cnt, int* __restrict__ start, int* __restrict__ bsum)
{
    __shared__ int sh[1024];
    int tid = threadIdx.x;
    int i = blockIdx.x * 1024 + tid;
    int v = (i < NSEG) ? cnt[i] : 0;
    sh[tid] = v;
    __syncthreads();
    for (int off = 1; off < 1024; off <<= 1) {
        int t = (tid >= off) ? sh[tid - off] : 0;
        __syncthreads();
        sh[tid] += t;
        __syncthreads();
    }
    if (i < NSEG) start[i] = sh[tid] - v;
    if (tid == 1023) bsum[blockIdx.x] = sh[1023];
}

// Scan P2: exclusive scan of block totals (single block)
__global__ __launch_bounds__(128) void scan_p2(int* __restrict__ bsum)
{
    __shared__ int sh[128];
    int tid = threadIdx.x;
    int v = (tid < NB1) ? bsum[tid] : 0;
    sh[tid] = v;
    __syncthreads();
    for (int off = 1; off < 128; off <<= 1) {
        int t = (tid >= off) ? sh[tid - off] : 0;
        __syncthreads();
        sh[tid] += t;
        __syncthreads();
    }
    if (tid < NB1) bsum[tid] = sh[tid] - v;
}

// Scan P3: add block offsets
__global__ __launch_bounds__(1024) void scan_p3(
    int* __restrict__ start, const int* __restrict__ bsum)
{
    int i = blockIdx.x * 1024 + threadIdx.x;
    if (i < NSEG) start[i] += bsum[blockIdx.x];
}

// Phase C: scatter point ids into segment-ordered list; start[] becomes end[]
__global__ __launch_bounds__(256) void phase_c(
    const int* __restrict__ rank, int* __restrict__ start, int* __restrict__ order)
{
    int p = blockIdx.x * 256 + threadIdx.x;
    if (p >= TOTP) return;
    int seg = rank[p];
    if (seg < 0) return;
    int pos = atomicAdd(&start[seg], 1);
    order[pos] = p;
}

// global_load_lds: lane l copies 4B from gp[l] -> ldsbase + l*4 (256B row DMA)
#define DMA_ROW(gp, lp) \
    __builtin_amdgcn_global_load_lds( \
        (const __attribute__((address_space(1))) void*)(gp), \
        (__attribute__((address_space(3))) void*)(lp), 4, 0, 0)

// ---------------------------------------------------------------------------
// Phase D: 32 voxels per block (8/wave). Stage point ids in LDS, then DMA
// point feature rows directly global->LDS via global_load_lds in rounds of
// RND=32 points per wave (one instruction per point: 64 lanes x 4B = the
// whole 256B row into a contiguous LDS slot; async, no VGPR writeback).
// s_waitcnt vmcnt(0) once per round, then segment-reduce the round from LDS
// into 8 per-lane float4 register accumulators (compile-time indexed).
// shfl_xor(16,32) cross-subgroup reduce, LDS transpose tile, coalesced
// out[b][c][xy] writes. No atomics.
// ---------------------------------------------------------------------------
__global__ __launch_bounds__(256) void phase_d(
    const int* __restrict__ endp, const int* __restrict__ order,
    const float* __restrict__ x, float* __restrict__ out)
{
    __shared__ int   ord_sh[4][CAP];       // 8 KB
    __shared__ float pbuf[4][RND][Cc];     // 32 KB: staged rows, per wave
    __shared__ float tile[32][68];         // 8.5 KB
    int blk  = blockIdx.x;                 // 0 .. 2499
    int b    = blk / (NVOX/32);            // 1250 blocks per batch
    int xy0  = (blk % (NVOX/32)) * 32;
    int wv   = threadIdx.x >> 6;           // 0..3
    int lane = threadIdx.x & 63;
    int seg0 = b * NVOX + xy0 + wv * 8;    // this wave's first voxel

    // lane j<9 loads boundary end[seg0-1+j]; e[v]=begin of voxel v, e[v+1]=end
    int e = 0;
    if (lane < 9) {
        int idx = seg0 - 1 + lane;
        e = (idx >= 0) ? endp[idx] : 0;
    }
    int eb0 = __shfl(e, 0);
    int rb[9];                             // voxel boundaries relative to eb0
    #pragma unroll
    for (int j = 0; j < 9; ++j) rb[j] = __shfl(e, j) - eb0;
    int count = rb[8];

    int g = lane >> 4;                     // point subgroup 0..3
    int q = (lane & 15) * 4;               // channel base for this lane

    float4 A[8];
    #pragma unroll
    for (int v = 0; v < 8; ++v) A[v] = make_float4(0.f, 0.f, 0.f, 0.f);

    if (count <= CAP) {                    // ~always (avg 66, CAP=512)
        // stage point ids (coalesced)
        for (int i = lane; i < count; i += 64)
            ord_sh[wv][i] = order[eb0 + i];

        for (int base = 0; base < count; base += RND) {
            int n = count - base; if (n > RND) n = RND;
            // read up to 32 pids into lanes 0..31, broadcast via readlane
            int pidv = 0;
            if (lane < RND) pidv = ord_sh[wv][base + lane];
            #pragma unroll
            for (int j = 0; j < RND; ++j) {
                if (base + j < count) {    // wave-uniform predicate
                    int spid = __builtin_amdgcn_readlane(pidv, j);
                    const float* gp = x + (size_t)spid * Cc + lane;
                    DMA_ROW(gp, &pbuf[wv][j][0]);
                }
            }
            asm volatile("s_waitcnt vmcnt(0)" ::: "memory");  // rows landed
            // segment-reduce this round from LDS (wave-private, no barrier)
            #pragma unroll
            for (int v = 0; v < 8; ++v) {
                int lo = rb[v]   - base; if (lo < 0) lo = 0;
                int hi = rb[v+1] - base; if (hi > n) hi = n;
                for (int t = lo + g; t < hi; t += 4) {
                    const float4 a = *(const float4*)&pbuf[wv][t][q];
                    A[v].x += a.x; A[v].y += a.y;
                    A[v].z += a.z; A[v].w += a.w;
                }
            }
        }
    } else {                               // fallback: per-voxel global gather
        #pragma unroll
        for (int v = 0; v < 8; ++v) {
            int begin = eb0 + rb[v];
            int endv  = eb0 + rb[v+1];
            for (int t = begin + g; t < endv; t += 4) {
                int p0 = order[t];
                const float4 a0 = *(const float4*)(x + (long)p0 * Cc + q);
                A[v].x += a0.x; A[v].y += a0.y;
                A[v].z += a0.z; A[v].w += a0.w;
            }
        }
    }

    // cross-subgroup reduce; lanes g==0 hold finals for channels q..q+3
    #pragma unroll
    for (int v = 0; v < 8; ++v) {
        A[v].x += __shfl_xor(A[v].x, 16); A[v].y += __shfl_xor(A[v].y, 16);
        A[v].z += __shfl_xor(A[v].z, 16); A[v].w += __shfl_xor(A[v].w, 16);
        A[v].x += __shfl_xor(A[v].x, 32); A[v].y += __shfl_xor(A[v].y, 32);
        A[v].z += __shfl_xor(A[v].z, 32); A[v].w += __shfl_xor(A[v].w, 32);
    }
    if (g == 0) {
        #pragma unroll
        for (int v = 0; v < 8; ++v)
            *(float4*)&tile[wv*8 + v][q] = A[v];
    }
    __syncthreads();

    // out[b][c][xy0+xy]: iteration s writes 8 channels x 32 xy
    float* dst = out + (long)b * Cc * NVOX + xy0;
    int xy = threadIdx.x & 31;
    int c0 = threadIdx.x >> 5;             // 0..7
    #pragma unroll
    for (int s = 0; s < 8; ++s) {
        int c = s * 8 + c0;
        dst[(long)c * NVOX + xy] = tile[xy][c];
    }
}

// ---------------------------------------------------------------------------
// Fallback (r1 atomic path) if ws is unexpectedly small
// ---------------------------------------------------------------------------
__global__ __launch_bounds__(256) void fiery_scatter_direct(
    const float* __restrict__ x, const float* __restrict__ geom,
    float* __restrict__ out)
{
    int wid  = blockIdx.x * 4 + (threadIdx.x >> 6);
    int lane = threadIdx.x & 63;
    if (wid >= TOTP) return;
    long gb = (long)wid * 3;
    float gx = geom[gb+0], gy = geom[gb+1], gz = geom[gb+2];
    int vx = (int)((gx + 50.0f) / 0.5f);
    int vy = (int)((gy + 50.0f) / 0.5f);
    int vz = (int)((gz + 10.0f) / 20.0f);
    if (!(vx >= 0 && vx < Xd && vy >= 0 && vy < Yd && vz == 0)) return;
    int b = (wid >= NP) ? 1 : 0;
    float vv = x[(long)wid * Cc + lane];
    long dst = ((long)(b * Cc + lane)) * NVOX + (vx * Yd + vy);
    atomicAdd(&out[dst], vv);
}

extern "C" void kernel_launch(void* const* d_in, const int* in_sizes, int n_in,
                              void* d_out, int out_size, void* d_ws, size_t ws_size,
                              hipStream_t stream)
{
    const float* x    = (const float*)d_in[0];
    const float* geom = (const float*)d_in[1];
    float* out = (float*)d_out;

    // ws layout: rank[TOTP] | order[TOTP] | cnt[NSEG] | start[NSEG] | bsum[128]
    size_t need = ((size_t)TOTP * 2 + (size_t)NSEG * 2 + 128) * sizeof(int);
    if (ws_size >= need) {
        int* rank  = (int*)d_ws;
        int* order = rank  + TOTP;
        int* cnt   = order + TOTP;
        int* start = cnt   + NSEG;
        int* bsum  = start + NSEG;

        zero_cnt<<<NB1, 1024, 0, stream>>>(cnt);
        phase_a<<<TOTP/256, 256, 0, stream>>>(geom, rank, cnt);
        scan_p1<<<NB1, 1024, 0, stream>>>(cnt, start, bsum);
        scan_p2<<<1, 128, 0, stream>>>(bsum);
        scan_p3<<<NB1, 1024, 0, stream>>>(start, bsum);
        phase_c<<<TOTP/256, 256, 0, stream>>>(rank, start, order);
        phase_d<<<Bq*(NVOX/32), 256, 0, stream>>>(start, order, x, out);
    } else {
        hipMemsetAsync(out, 0, (size_t)out_size * sizeof(float), stream);
        fiery_scatter_direct<<<TOTP/4, 256, 0, stream>>>(x, geom, out);
    }
}